// Round 6
// baseline (368.221 us; speedup 1.0000x reference)
//
#include <hip/hip_runtime.h>
#include <stdint.h>

#define B_ 4
#define L_ 4096
#define H_ 8
#define D_ 64
#define S_ 45
#define U_ 45
#define BH_ 32
#define KC_ 32                     // split-k chunks
#define CL_ 128                    // keys per chunk
#define STRIDE_ (H_*D_)            // 512 floats between consecutive l
#define BSTR_ ((size_t)L_*H_*D_)   // 2097152 floats per batch

// index_sample declared int64 in the reference; harness may pass int32 or int64.
__device__ __forceinline__ bool detect_idx64(const int* idxp){
    bool z = true;
    #pragma unroll
    for (int i = 1; i < 32; i += 2) z = z && (idxp[i] == 0);
    return z;
}

// ---------- kernel A: M[bh][q] = max_s(dot) - sum_s(dot)/L ----------
// 8 lanes per gathered K-row (2 full-line requests/row). At the empirical
// random-gather L2 ceiling (~17 TB/s); see R5 post-mortem.
__global__ __launch_bounds__(256) void kM(const float* __restrict__ Qb,
                                          const float* __restrict__ Kb,
                                          const int* __restrict__ idxp,
                                          float* __restrict__ Mout){
    int g = blockIdx.x;                 // 0..2047
    int xcd  = g & 7;
    int slot = g >> 3;                  // 0..255
    int bh   = xcd*4 + (slot >> 6);     // bh varies slowest within an XCD
    int chunk= slot & 63;               // 64-query chunk
    int b = bh >> 3, h = bh & 7;
    int q0 = chunk * 64;
    bool idx64 = detect_idx64(idxp);

    __shared__ float qs[64][64];        // 16 KB Q tile
    for (int i = threadIdx.x; i < 64*16; i += 256){
        int qrow = i >> 4, c = i & 15;
        float4 v = ((const float4*)(Qb + (size_t)b*BSTR_ + (size_t)(q0+qrow)*STRIDE_ + h*D_))[c];
        *(float4*)&qs[qrow][c*4] = v;
    }
    __syncthreads();

    int lane8 = threadIdx.x & 7;
    const float* kbase = Kb + (size_t)b*BSTR_ + h*D_;

    for (int qq = 0; qq < 2; qq++){
        int qrow = (threadIdx.x >> 3) + 32*qq;   // 0..63
        int qg   = q0 + qrow;
        float4 qf0 = *(const float4*)&qs[qrow][lane8*4];
        float4 qf1 = *(const float4*)&qs[qrow][lane8*4 + 32];
        float mx = -1e30f, sm = 0.f;
        #pragma unroll 3
        for (int s = 0; s < S_; s++){
            int flat = qg * S_ + s;
            int ki = idx64 ? idxp[2*flat] : idxp[flat];
            const float* kr = kbase + (size_t)ki*STRIDE_;
            float4 k0 = *(const float4*)(kr + lane8*4);
            float4 k1 = *(const float4*)(kr + lane8*4 + 32);
            float a0 = qf0.x*k0.x;
            a0 = fmaf(qf0.y, k0.y, a0);
            a0 = fmaf(qf0.z, k0.z, a0);
            a0 = fmaf(qf0.w, k0.w, a0);
            float a1 = qf1.x*k1.x;
            a1 = fmaf(qf1.y, k1.y, a1);
            a1 = fmaf(qf1.z, k1.z, a1);
            a1 = fmaf(qf1.w, k1.w, a1);
            float p = a0 + a1;
            p += __shfl_xor(p, 1);
            p += __shfl_xor(p, 2);
            p += __shfl_xor(p, 4);
            mx = fmaxf(mx, p); sm += p;
        }
        if (lane8 == 0) Mout[bh * L_ + qg] = mx - sm * (1.0f / L_);
    }
}

// ---------- fused top-45 per (b,h) + selRow map + mean zero ----------
__global__ __launch_bounds__(512) void kTopF(const float* __restrict__ M,
                                             int* __restrict__ Mtop,
                                             float* __restrict__ meanZ,
                                             int* __restrict__ selRow){
    int bh = blockIdx.x;
    int t = threadIdx.x;
    if (t < 64) meanZ[bh*64 + t] = 0.f;
    for (int j = t; j < L_; j += 512) selRow[(size_t)bh*L_ + j] = 0;

    __shared__ float cV[8*U_];
    __shared__ int   cI[8*U_];
    int wv = t >> 6, lane = t & 63;      // wv = segment 0..7
    const float* Mr = M + (size_t)bh*L_ + wv*512;
    float v[8];
    #pragma unroll
    for (int j = 0; j < 8; j++) v[j] = Mr[lane + 64*j];

    for (int it = 0; it < U_; it++){
        float best = -1e30f; int bidx = 0x7fffffff;
        #pragma unroll
        for (int j = 0; j < 8; j++){
            int id = lane + 64*j;
            if (v[j] > best){ best = v[j]; bidx = id; }   // ascending id scan
        }
        #pragma unroll
        for (int off = 1; off < 64; off <<= 1){
            float ov = __shfl_xor(best, off); int oi = __shfl_xor(bidx, off);
            if (ov > best || (ov == best && oi < bidx)){ best = ov; bidx = oi; }
        }
        if (lane == 0){ cV[wv*U_ + it] = best; cI[wv*U_ + it] = wv*512 + bidx; }
        if (lane == (bidx & 63)) v[bidx >> 6] = -1e30f;
    }
    __syncthreads();
    if (t < 64){
        float v2[6]; int id2[6];
        #pragma unroll
        for (int j = 0; j < 6; j++){
            int slot = t + 64*j;
            if (slot < 8*U_){ v2[j] = cV[slot]; id2[j] = cI[slot]; }
            else            { v2[j] = -1e30f;  id2[j] = 0x7fffffff; }
        }
        for (int it = 0; it < U_; it++){
            float best = -1e30f; int bidx = 0x7fffffff; int bj = 0;
            #pragma unroll
            for (int j = 0; j < 6; j++){
                if (v2[j] > best || (v2[j] == best && id2[j] < bidx)){
                    best = v2[j]; bidx = id2[j]; bj = j;
                }
            }
            float myBest = best; int myIdx = bidx;
            #pragma unroll
            for (int off = 1; off < 64; off <<= 1){
                float ov = __shfl_xor(best, off); int oi = __shfl_xor(bidx, off);
                if (ov > best || (ov == best && oi < bidx)){ best = ov; bidx = oi; }
            }
            if (t == 0){
                Mtop[bh*U_ + it] = bidx;
                selRow[(size_t)bh*L_ + bidx] = it + 1;
            }
            if (myBest == best && myIdx == bidx) v2[bj] = -1e30f;  // unique owner
        }
    }
}

// ---------- fused flash split-k: scores + softmax partials + PV + V-sum ----------
// Grid (kc=32, bh=32) = 1024 blocks, 256 threads, ~34 KB LDS -> 4 blocks/CU,
// 16 waves/CU (vs 8 in the 16-chunk version).
__global__ __launch_bounds__(256) void kAttnPart(const float* __restrict__ Qb,
                                                 const float* __restrict__ Kb,
                                                 const float* __restrict__ Vb,
                                                 const int*   __restrict__ Mtop,
                                                 float* __restrict__ Opart,
                                                 float* __restrict__ mlG,
                                                 float* __restrict__ mean){
    int bh = blockIdx.y, b = bh >> 3, h = bh & 7; int kc = blockIdx.x;
    int t = threadIdx.x;
    __shared__ float S[48][132];          // 25.3 KB (rows 45..47 scratch)
    __shared__ float red[4][8][64];       // 8 KB
    __shared__ int   qidx[U_];

    if (t < U_) qidx[t] = Mtop[bh*U_ + t];
    __syncthreads();

    // Phase 1: scores for this block's 128 keys; two 128-thread groups
    // split the 45 queries (group0: u<23, group1: u>=23).
    int kloc = t & 127;
    int grp  = t >> 7;
    int k = kc*CL_ + kloc;
    float4 kf[16];
    const float4* K4 = (const float4*)(Kb + (size_t)b*BSTR_ + (size_t)k*STRIDE_ + h*D_);
    #pragma unroll
    for (int c = 0; c < 16; c++) kf[c] = K4[c];
    int ub = grp ? 23 : 0, ue = grp ? 45 : 23;
    #pragma unroll 2
    for (int u = ub; u < ue; u++){
        int qi = __builtin_amdgcn_readfirstlane(qidx[u]);   // wave-uniform
        const float4* qp = (const float4*)(Qb + (size_t)b*BSTR_ + (size_t)qi*STRIDE_ + h*D_);
        float a0=0.f, a1=0.f, a2=0.f, a3=0.f;
        #pragma unroll
        for (int c = 0; c < 16; c++){
            float4 qv = qp[c];
            a0 = fmaf(qv.x, kf[c].x, a0);
            a1 = fmaf(qv.y, kf[c].y, a1);
            a2 = fmaf(qv.z, kf[c].z, a2);
            a3 = fmaf(qv.w, kf[c].w, a3);
        }
        S[u][kloc] = ((a0+a1)+(a2+a3)) * 0.125f;
    }
    __syncthreads();

    // Phase 2: per-u softmax partial over 128 scores; two 32-lane halves/wave.
    int wv = t >> 6, lane = t & 63;
    int half = lane >> 5, l32 = lane & 31;
    for (int u = wv*2 + half; u < U_; u += 8){
        float4 sv = *(const float4*)&S[u][l32*4];
        float m = fmaxf(fmaxf(sv.x, sv.y), fmaxf(sv.z, sv.w));
        #pragma unroll
        for (int off = 1; off < 32; off <<= 1) m = fmaxf(m, __shfl_xor(m, off));
        float e0 = __expf(sv.x - m), e1 = __expf(sv.y - m);
        float e2 = __expf(sv.z - m), e3 = __expf(sv.w - m);
        float ls = (e0+e1)+(e2+e3);
        #pragma unroll
        for (int off = 1; off < 32; off <<= 1) ls += __shfl_xor(ls, off);
        float4 pv; pv.x = e0; pv.y = e1; pv.z = e2; pv.w = e3;
        *(float4*)&S[u][l32*4] = pv;
        if (l32 == 0){
            size_t mi = ((size_t)(bh*KC_ + kc)*U_ + u)*2;
            mlG[mi] = m; mlG[mi+1] = ls;
        }
    }
    __syncthreads();

    // Phase 3: Opart[u][d] = sum_k P[u][k]*V[k][d]; V column-sum folded in g==0.
    int d8 = t & 7, ks = t >> 3;          // ks 0..31 (8 per wave)
    float vsum[8];
    #pragma unroll
    for (int j = 0; j < 8; j++) vsum[j] = 0.f;
    for (int g = 0; g < 6; g++){
        int u0 = g*8; int nu = (U_ - u0 < 8) ? (U_ - u0) : 8;
        float acc[8][8];
        #pragma unroll
        for (int r = 0; r < 8; r++)
            #pragma unroll
            for (int j = 0; j < 8; j++) acc[r][j] = 0.f;
        for (int i = 0; i < 4; i++){
            int kk = ks + 32*i;
            const float4* V4 = (const float4*)(Vb + (size_t)b*BSTR_ +
                        (size_t)(kc*CL_ + kk)*STRIDE_ + h*D_);
            float4 va = V4[d8*2], vb = V4[d8*2+1];
            float vf[8] = {va.x, va.y, va.z, va.w, vb.x, vb.y, vb.z, vb.w};
            if (g == 0){
                #pragma unroll
                for (int j = 0; j < 8; j++) vsum[j] += vf[j];
            }
            #pragma unroll
            for (int r = 0; r < 8; r++){
                float p = S[u0+r][kk];    // rows >= nu: scratch, discarded below
                #pragma unroll
                for (int j = 0; j < 8; j++) acc[r][j] = fmaf(p, vf[j], acc[r][j]);
            }
        }
        #pragma unroll
        for (int off = 8; off <= 32; off <<= 1)
            #pragma unroll
            for (int r = 0; r < 8; r++)
                #pragma unroll
                for (int j = 0; j < 8; j++) acc[r][j] += __shfl_xor(acc[r][j], off);
        if (lane < 8){
            for (int r = 0; r < 8; r++)
                #pragma unroll
                for (int j = 0; j < 8; j++) red[wv][r][d8*8+j] = acc[r][j];
        }
        __syncthreads();
        for (int tt = t; tt < nu*64; tt += 256){
            int r = tt >> 6, d = tt & 63;
            float s = red[0][r][d] + red[1][r][d] + red[2][r][d] + red[3][r][d];
            Opart[((size_t)(bh*KC_ + kc)*U_ + u0 + r)*64 + d] = s;
        }
        __syncthreads();
    }
    // V column-sum -> mean (SUM).
    #pragma unroll
    for (int off = 8; off <= 32; off <<= 1)
        #pragma unroll
        for (int j = 0; j < 8; j++) vsum[j] += __shfl_xor(vsum[j], off);
    if (lane < 8){
        #pragma unroll
        for (int j = 0; j < 8; j++) red[wv][0][lane*8 + j] = vsum[j];
    }
    __syncthreads();
    if (t < 64){
        float s = red[0][0][t] + red[1][0][t] + red[2][0][t] + red[3][0][t];
        atomicAdd(&mean[bh*64 + t], s);
    }
}

// ---------- fused output: mean fill + split-k merge scatter ----------
__global__ __launch_bounds__(256) void kOut(const float* __restrict__ mean,
                                            const int*   __restrict__ selRow,
                                            const float* __restrict__ mlG,
                                            const float* __restrict__ Opart,
                                            float* __restrict__ out){
    size_t t = (size_t)blockIdx.x*256 + threadIdx.x;   // one float4; 2,097,152 total
    int d16 = (int)(t & 15); int h = (int)((t >> 4) & 7);
    int l   = (int)((t >> 7) & 4095); int b = (int)(t >> 19);
    int bh = b*8 + h;
    int sel = selRow[(size_t)bh*L_ + l];
    float4 o;
    if (sel == 0){
        o = *(const float4*)(mean + bh*64 + d16*4);
        const float inv = 1.0f / L_;
        o.x *= inv; o.y *= inv; o.z *= inv; o.w *= inv;
    } else {
        int u = sel - 1;
        float mstar = -1e30f;
        #pragma unroll 8
        for (int kc = 0; kc < KC_; kc++)
            mstar = fmaxf(mstar, mlG[((size_t)(bh*KC_ + kc)*U_ + u)*2]);
        float lsum = 0.f;
        float4 acc; acc.x = acc.y = acc.z = acc.w = 0.f;
        #pragma unroll 8
        for (int kc = 0; kc < KC_; kc++){
            size_t mi = ((size_t)(bh*KC_ + kc)*U_ + u)*2;
            float w = __expf(mlG[mi] - mstar);
            lsum = fmaf(mlG[mi+1], w, lsum);
            float4 op = *(const float4*)(Opart + ((size_t)(bh*KC_ + kc)*U_ + u)*64 + d16*4);
            acc.x = fmaf(w, op.x, acc.x);
            acc.y = fmaf(w, op.y, acc.y);
            acc.z = fmaf(w, op.z, acc.z);
            acc.w = fmaf(w, op.w, acc.w);
        }
        float inv = 1.0f / lsum;
        acc.x *= inv; acc.y *= inv; acc.z *= inv; acc.w *= inv;
        o = acc;
    }
    ((float4*)out)[t] = o;
}

extern "C" void kernel_launch(void* const* d_in, const int* in_sizes, int n_in,
                              void* d_out, int out_size, void* d_ws, size_t ws_size,
                              hipStream_t stream) {
    const float* Qb  = (const float*)d_in[0];
    const float* Kb  = (const float*)d_in[1];
    const float* Vb  = (const float*)d_in[2];
    const int*   idx = (const int*)d_in[3];
    float* out = (float*)d_out;

    float* ws = (float*)d_ws;
    // ws layout (float offsets)
    float* M      = ws;                      // 131072
    int*   Mtop   = (int*)(ws + 131072);     // 1440 (pad 2048)
    float* mean   = ws + 133120;             // 2048 (SUM; zeroed in kTopF, scaled in kOut)
    int*   selRow = (int*)(ws + 135168);     // 131072
    float* mlG    = ws + 266240;             // 32*32*45*2 = 92160
    float* Opart  = ws + 358400;             // 32*32*45*64 = 2949120
    // total = 3,307,520 floats = 13.2 MB

    kM        <<<dim3(2048),     dim3(256), 0, stream>>>(Qb, Kb, idx, M);
    kTopF     <<<dim3(32),       dim3(512), 0, stream>>>(M, Mtop, mean, selRow);
    kAttnPart <<<dim3(KC_, 32),  dim3(256), 0, stream>>>(Qb, Kb, Vb, Mtop, Opart, mlG, mean);
    kOut      <<<dim3(8192),     dim3(256), 0, stream>>>(mean, selRow, mlG, Opart, out);
}

// Round 8
// 343.415 us; speedup vs baseline: 1.0722x; 1.0722x over previous
//
#include <hip/hip_runtime.h>
#include <stdint.h>

#define B_ 4
#define L_ 4096
#define H_ 8
#define D_ 64
#define S_ 45
#define U_ 45
#define BH_ 32
#define KC_ 16                     // split-k chunks (256 keys each)
#define STRIDE_ (H_*D_)            // 512 floats between consecutive l
#define BSTR_ ((size_t)L_*H_*D_)   // 2097152 floats per batch

// index_sample declared int64 in the reference; harness may pass int32 or int64.
__device__ __forceinline__ bool detect_idx64(const int* idxp){
    bool z = true;
    #pragma unroll
    for (int i = 1; i < 32; i += 2) z = z && (idxp[i] == 0);
    return z;
}

// ---------- kernel A: M[bh][q] = max_s(dot) - sum_s(dot)/L ----------
// 8 lanes per gathered K-row (2 full-line requests/row). At the empirical
// random-gather L2 plateau (~17 TB/s effective; 3 instruction-mix variants
// all land 86-97 us). Keep standalone at 2048 blocks / high occupancy.
__global__ __launch_bounds__(256) void kM(const float* __restrict__ Qb,
                                          const float* __restrict__ Kb,
                                          const int* __restrict__ idxp,
                                          float* __restrict__ Mout){
    int g = blockIdx.x;                 // 0..2047
    int xcd  = g & 7;
    int slot = g >> 3;                  // 0..255
    int bh   = xcd*4 + (slot >> 6);     // bh varies slowest within an XCD
    int chunk= slot & 63;               // 64-query chunk
    int b = bh >> 3, h = bh & 7;
    int q0 = chunk * 64;
    bool idx64 = detect_idx64(idxp);

    __shared__ float qs[64][64];        // 16 KB Q tile
    for (int i = threadIdx.x; i < 64*16; i += 256){
        int qrow = i >> 4, c = i & 15;
        float4 v = ((const float4*)(Qb + (size_t)b*BSTR_ + (size_t)(q0+qrow)*STRIDE_ + h*D_))[c];
        *(float4*)&qs[qrow][c*4] = v;
    }
    __syncthreads();

    int lane8 = threadIdx.x & 7;
    const float* kbase = Kb + (size_t)b*BSTR_ + h*D_;

    for (int qq = 0; qq < 2; qq++){
        int qrow = (threadIdx.x >> 3) + 32*qq;   // 0..63
        int qg   = q0 + qrow;
        float4 qf0 = *(const float4*)&qs[qrow][lane8*4];
        float4 qf1 = *(const float4*)&qs[qrow][lane8*4 + 32];
        float mx = -1e30f, sm = 0.f;
        #pragma unroll 3
        for (int s = 0; s < S_; s++){
            int flat = qg * S_ + s;
            int ki = idx64 ? idxp[2*flat] : idxp[flat];
            const float* kr = kbase + (size_t)ki*STRIDE_;
            float4 k0 = *(const float4*)(kr + lane8*4);
            float4 k1 = *(const float4*)(kr + lane8*4 + 32);
            float a0 = qf0.x*k0.x;
            a0 = fmaf(qf0.y, k0.y, a0);
            a0 = fmaf(qf0.z, k0.z, a0);
            a0 = fmaf(qf0.w, k0.w, a0);
            float a1 = qf1.x*k1.x;
            a1 = fmaf(qf1.y, k1.y, a1);
            a1 = fmaf(qf1.z, k1.z, a1);
            a1 = fmaf(qf1.w, k1.w, a1);
            float p = a0 + a1;
            p += __shfl_xor(p, 1);
            p += __shfl_xor(p, 2);
            p += __shfl_xor(p, 4);
            mx = fmaxf(mx, p); sm += p;
        }
        if (lane8 == 0) Mout[bh * L_ + qg] = mx - sm * (1.0f / L_);
    }
}

// ---------- fused top-45 per (b,h) + selRow map + mean zero ----------
__global__ __launch_bounds__(512) void kTopF(const float* __restrict__ M,
                                             int* __restrict__ Mtop,
                                             float* __restrict__ meanZ,
                                             int* __restrict__ selRow){
    int bh = blockIdx.x;
    int t = threadIdx.x;
    if (t < 64) meanZ[bh*64 + t] = 0.f;
    for (int j = t; j < L_; j += 512) selRow[(size_t)bh*L_ + j] = 0;

    __shared__ float cV[8*U_];
    __shared__ int   cI[8*U_];
    int wv = t >> 6, lane = t & 63;      // wv = segment 0..7
    const float* Mr = M + (size_t)bh*L_ + wv*512;
    float v[8];
    #pragma unroll
    for (int j = 0; j < 8; j++) v[j] = Mr[lane + 64*j];

    for (int it = 0; it < U_; it++){
        float best = -1e30f; int bidx = 0x7fffffff;
        #pragma unroll
        for (int j = 0; j < 8; j++){
            int id = lane + 64*j;
            if (v[j] > best){ best = v[j]; bidx = id; }   // ascending id scan
        }
        #pragma unroll
        for (int off = 1; off < 64; off <<= 1){
            float ov = __shfl_xor(best, off); int oi = __shfl_xor(bidx, off);
            if (ov > best || (ov == best && oi < bidx)){ best = ov; bidx = oi; }
        }
        if (lane == 0){ cV[wv*U_ + it] = best; cI[wv*U_ + it] = wv*512 + bidx; }
        if (lane == (bidx & 63)) v[bidx >> 6] = -1e30f;
    }
    __syncthreads();
    if (t < 64){
        float v2[6]; int id2[6];
        #pragma unroll
        for (int j = 0; j < 6; j++){
            int slot = t + 64*j;
            if (slot < 8*U_){ v2[j] = cV[slot]; id2[j] = cI[slot]; }
            else            { v2[j] = -1e30f;  id2[j] = 0x7fffffff; }
        }
        for (int it = 0; it < U_; it++){
            float best = -1e30f; int bidx = 0x7fffffff; int bj = 0;
            #pragma unroll
            for (int j = 0; j < 6; j++){
                if (v2[j] > best || (v2[j] == best && id2[j] < bidx)){
                    best = v2[j]; bidx = id2[j]; bj = j;
                }
            }
            float myBest = best; int myIdx = bidx;
            #pragma unroll
            for (int off = 1; off < 64; off <<= 1){
                float ov = __shfl_xor(best, off); int oi = __shfl_xor(bidx, off);
                if (ov > best || (ov == best && oi < bidx)){ best = ov; bidx = oi; }
            }
            if (t == 0){
                Mtop[bh*U_ + it] = bidx;
                selRow[(size_t)bh*L_ + bidx] = it + 1;
            }
            if (myBest == best && myIdx == bidx) v2[bj] = -1e30f;  // unique owner
        }
    }
}

// ---------- fused flash split-k+u: scores + softmax partials + PV + V-sum ----------
// Grid (kc=16, bh=32, uh=2) = 1024 blocks, 256 threads, ~33 KB LDS ->
// 4 blocks/CU capacity with grid exactly 4/CU (16 waves/CU). Each block:
// its own 256-key chunk (K frags loaded once), 23/22 of the 45 queries.
__global__ __launch_bounds__(256) void kAttnPart(const float* __restrict__ Qb,
                                                 const float* __restrict__ Kb,
                                                 const float* __restrict__ Vb,
                                                 const int*   __restrict__ Mtop,
                                                 float* __restrict__ Opart,
                                                 float* __restrict__ mlG,
                                                 float* __restrict__ mean){
    int bh = blockIdx.y, b = bh >> 3, h = bh & 7;
    int kc = blockIdx.x, uh = blockIdx.z;
    int u0 = uh ? 23 : 0;
    int nu = uh ? 22 : 23;
    int t = threadIdx.x;
    __shared__ float S[24][260];          // 24.4 KB (rows >= nu scratch)
    __shared__ float red[4][8][64];       // 8 KB
    __shared__ int   qidx[23];

    if (t < nu) qidx[t] = Mtop[bh*U_ + u0 + t];
    __syncthreads();

    // Phase 1: scores for this block's 256 keys, its nu queries.
    int k = kc*256 + t;
    float4 kf[16];
    const float4* K4 = (const float4*)(Kb + (size_t)b*BSTR_ + (size_t)k*STRIDE_ + h*D_);
    #pragma unroll
    for (int c = 0; c < 16; c++) kf[c] = K4[c];
    for (int u = 0; u < nu; u++){
        int qi = __builtin_amdgcn_readfirstlane(qidx[u]);   // wave-uniform -> scalar loads
        const float4* qp = (const float4*)(Qb + (size_t)b*BSTR_ + (size_t)qi*STRIDE_ + h*D_);
        float a0=0.f, a1=0.f, a2=0.f, a3=0.f;
        #pragma unroll
        for (int c = 0; c < 16; c++){
            float4 qv = qp[c];
            a0 = fmaf(qv.x, kf[c].x, a0);
            a1 = fmaf(qv.y, kf[c].y, a1);
            a2 = fmaf(qv.z, kf[c].z, a2);
            a3 = fmaf(qv.w, kf[c].w, a3);
        }
        S[u][t] = ((a0+a1)+(a2+a3)) * 0.125f;
    }
    __syncthreads();

    // Phase 2: per-u softmax partial over 256 scores (one wave per u).
    int wv = t >> 6, lane = t & 63;
    for (int u = wv; u < nu; u += 4){
        float4 sv = *(const float4*)&S[u][lane*4];
        float m = fmaxf(fmaxf(sv.x, sv.y), fmaxf(sv.z, sv.w));
        #pragma unroll
        for (int off = 1; off < 64; off <<= 1) m = fmaxf(m, __shfl_xor(m, off));
        float e0 = __expf(sv.x - m), e1 = __expf(sv.y - m);
        float e2 = __expf(sv.z - m), e3 = __expf(sv.w - m);
        float ls = (e0+e1)+(e2+e3);
        #pragma unroll
        for (int off = 1; off < 64; off <<= 1) ls += __shfl_xor(ls, off);
        float4 pv; pv.x = e0; pv.y = e1; pv.z = e2; pv.w = e3;
        *(float4*)&S[u][lane*4] = pv;
        if (lane == 0){
            size_t mi = ((size_t)(bh*KC_ + kc)*U_ + u0 + u)*2;
            mlG[mi] = m; mlG[mi+1] = ls;
        }
    }
    __syncthreads();

    // Phase 3: Opart[u][d] = sum_k P[u][k]*V[k][d]; V column-sum on uh==0, g==0.
    int d8 = t & 7, ks = t >> 3;          // ks 0..31
    float vsum[8];
    #pragma unroll
    for (int j = 0; j < 8; j++) vsum[j] = 0.f;
    for (int g = 0; g < 3; g++){
        int g0 = g*8; int nug = (nu - g0 < 8) ? (nu - g0) : 8;
        float acc[8][8];
        #pragma unroll
        for (int r = 0; r < 8; r++)
            #pragma unroll
            for (int j = 0; j < 8; j++) acc[r][j] = 0.f;
        for (int i = 0; i < 8; i++){
            int kk = ks + 32*i;
            const float4* V4 = (const float4*)(Vb + (size_t)b*BSTR_ +
                        (size_t)(kc*256 + kk)*STRIDE_ + h*D_);
            float4 va = V4[d8*2], vb = V4[d8*2+1];
            float vf[8] = {va.x, va.y, va.z, va.w, vb.x, vb.y, vb.z, vb.w};
            if (uh == 0 && g == 0){
                #pragma unroll
                for (int j = 0; j < 8; j++) vsum[j] += vf[j];
            }
            #pragma unroll
            for (int r = 0; r < 8; r++){
                float p = S[g0+r][kk];    // rows >= nu: scratch, discarded below
                #pragma unroll
                for (int j = 0; j < 8; j++) acc[r][j] = fmaf(p, vf[j], acc[r][j]);
            }
        }
        #pragma unroll
        for (int off = 8; off <= 32; off <<= 1)
            #pragma unroll
            for (int r = 0; r < 8; r++)
                #pragma unroll
                for (int j = 0; j < 8; j++) acc[r][j] += __shfl_xor(acc[r][j], off);
        if (lane < 8){
            for (int r = 0; r < 8; r++)
                #pragma unroll
                for (int j = 0; j < 8; j++) red[wv][r][d8*8+j] = acc[r][j];
        }
        __syncthreads();
        for (int tt = t; tt < nug*64; tt += 256){
            int r = tt >> 6, d = tt & 63;
            float s = red[0][r][d] + red[1][r][d] + red[2][r][d] + red[3][r][d];
            Opart[((size_t)(bh*KC_ + kc)*U_ + u0 + g0 + r)*64 + d] = s;
        }
        __syncthreads();
    }
    // V column-sum -> mean (SUM). Only uh==0 blocks contribute (no double count).
    if (uh == 0){
        #pragma unroll
        for (int off = 8; off <= 32; off <<= 1)
            #pragma unroll
            for (int j = 0; j < 8; j++) vsum[j] += __shfl_xor(vsum[j], off);
        if (lane < 8){
            #pragma unroll
            for (int j = 0; j < 8; j++) red[wv][0][lane*8 + j] = vsum[j];
        }
        __syncthreads();
        if (t < 64){
            float s = red[0][0][t] + red[1][0][t] + red[2][0][t] + red[3][0][t];
            atomicAdd(&mean[bh*64 + t], s);
        }
    }
}

// ---------- fused output: mean fill + split-k merge scatter ----------
__global__ __launch_bounds__(256) void kOut(const float* __restrict__ mean,
                                            const int*   __restrict__ selRow,
                                            const float* __restrict__ mlG,
                                            const float* __restrict__ Opart,
                                            float* __restrict__ out){
    size_t t = (size_t)blockIdx.x*256 + threadIdx.x;   // one float4; 2,097,152 total
    int d16 = (int)(t & 15); int h = (int)((t >> 4) & 7);
    int l   = (int)((t >> 7) & 4095); int b = (int)(t >> 19);
    int bh = b*8 + h;
    int sel = selRow[(size_t)bh*L_ + l];
    float4 o;
    if (sel == 0){
        o = *(const float4*)(mean + bh*64 + d16*4);
        const float inv = 1.0f / L_;
        o.x *= inv; o.y *= inv; o.z *= inv; o.w *= inv;
    } else {
        int u = sel - 1;
        float mstar = -1e30f;
        #pragma unroll
        for (int kc = 0; kc < KC_; kc++)
            mstar = fmaxf(mstar, mlG[((size_t)(bh*KC_ + kc)*U_ + u)*2]);
        float lsum = 0.f;
        float4 acc; acc.x = acc.y = acc.z = acc.w = 0.f;
        #pragma unroll
        for (int kc = 0; kc < KC_; kc++){
            size_t mi = ((size_t)(bh*KC_ + kc)*U_ + u)*2;
            float w = __expf(mlG[mi] - mstar);
            lsum = fmaf(mlG[mi+1], w, lsum);
            float4 op = *(const float4*)(Opart + ((size_t)(bh*KC_ + kc)*U_ + u)*64 + d16*4);
            acc.x = fmaf(w, op.x, acc.x);
            acc.y = fmaf(w, op.y, acc.y);
            acc.z = fmaf(w, op.z, acc.z);
            acc.w = fmaf(w, op.w, acc.w);
        }
        float inv = 1.0f / lsum;
        acc.x *= inv; acc.y *= inv; acc.z *= inv; acc.w *= inv;
        o = acc;
    }
    ((float4*)out)[t] = o;
}

extern "C" void kernel_launch(void* const* d_in, const int* in_sizes, int n_in,
                              void* d_out, int out_size, void* d_ws, size_t ws_size,
                              hipStream_t stream) {
    const float* Qb  = (const float*)d_in[0];
    const float* Kb  = (const float*)d_in[1];
    const float* Vb  = (const float*)d_in[2];
    const int*   idx = (const int*)d_in[3];
    float* out = (float*)d_out;

    float* ws = (float*)d_ws;
    // ws layout (float offsets)
    float* M      = ws;                      // 131072
    int*   Mtop   = (int*)(ws + 131072);     // 1440 (pad 2048)
    float* mean   = ws + 133120;             // 2048 (SUM; zeroed in kTopF, scaled in kOut)
    int*   selRow = (int*)(ws + 135168);     // 131072
    float* mlG    = ws + 266240;             // 32*16*45*2 = 46080 (pad 49152)
    float* Opart  = ws + 315392;             // 32*16*45*64 = 1474560
    // total = 1,789,952 floats = 7.2 MB

    kM        <<<dim3(2048),       dim3(256), 0, stream>>>(Qb, Kb, idx, M);
    kTopF     <<<dim3(32),         dim3(512), 0, stream>>>(M, Mtop, mean, selRow);
    kAttnPart <<<dim3(KC_, 32, 2), dim3(256), 0, stream>>>(Qb, Kb, Vb, Mtop, Opart, mlG, mean);
    kOut      <<<dim3(8192),       dim3(256), 0, stream>>>(mean, selRow, mlG, Opart, out);
}